// Round 2
// baseline (707.452 us; speedup 1.0000x reference)
//
#include <hip/hip_runtime.h>
#include <hip/hip_bf16.h>
#include <math.h>

#define N_NODES 500000
#define DIM 256
#define ADIM 64
#define NG 512
#define TILE 32
#define NTILES 15625      // 500000 / 32 exact, no partial tiles
#define GRID_F 768        // 3 blocks/CU * 256 CUs

typedef __attribute__((ext_vector_type(8))) short short8;
typedef __attribute__((ext_vector_type(4))) float floatx4;

// raw barrier: waits LDS ops only, does NOT drain vmcnt -> global prefetch
// stays in flight across it (m97 lesson / 8-phase discipline)
#define BAR() asm volatile("s_waitcnt lgkmcnt(0)\n\ts_barrier" ::: "memory")

__device__ inline unsigned short f2bf(float f) {
    union { float f; unsigned int u; } v; v.f = f;
    unsigned int u = v.u;
    unsigned int r = u + 0x7FFFu + ((u >> 16) & 1u);   // RNE
    return (unsigned short)(r >> 16);
}

__device__ inline unsigned pk_bf2(float a, float b) {
    __hip_bfloat162 h = __float22bfloat162_rn(make_float2(a, b));
    union { __hip_bfloat162 h; unsigned u; } cv; cv.h = h;
    return cv.u;
}

__device__ inline float tanh_fast(float xv) {
    float e = __expf(2.0f * fabsf(xv));
    float r = 1.0f - 2.0f * __builtin_amdgcn_rcpf(e + 1.0f);
    return copysignf(r, xv);
}

// ---------------- prep: transpose W_out, W_att->bf16, c=||ctx||_1, zero accum/ssum
__global__ __launch_bounds__(256) void k_prep(const float* __restrict__ W_out,
                                              const float* __restrict__ W_att,
                                              const float* __restrict__ ctx,
                                              float* __restrict__ Wt_out,
                                              unsigned short* __restrict__ Wbf,
                                              float* __restrict__ cnorm,
                                              float* __restrict__ zero_base) {
    int b = blockIdx.x, t = threadIdx.x;
    if (b < 256) {
        int idx = b * 256 + t;
        int o = idx >> 8, d = idx & 255;
        Wt_out[d * DIM + o] = W_out[idx];
    } else if (b < 320) {
        int idx = (b - 256) * 256 + t;
        Wbf[idx] = f2bf(W_att[idx]);
    } else if (b < 834) {
        int idx = (b - 320) * 256 + t;   // 514*256 == 131584 covers accum+ssum
        zero_base[idx] = 0.f;
    } else if (t == 0) {
        float s = 0.f;
        for (int k = 0; k < ADIM; ++k) s += fabsf(ctx[k]);
        *cnorm = s;
    }
}

// ---------------- fused streaming kernel: scores (MFMA) + exp + pooling.
// Persistent blocks over contiguous 32-node tiles, double-buffered LDS,
// issue-early/write-late reg staging, raw barriers (no vmcnt drain),
// register pool-accumulator flushed per segment change.
__global__ __launch_bounds__(256, 3) void k_fused(const float* __restrict__ x,
                                                  const unsigned short* __restrict__ Wbf,
                                                  const float* __restrict__ b_att,
                                                  const float* __restrict__ ctx,
                                                  const int* __restrict__ batch,
                                                  const float* __restrict__ cnorm,
                                                  float* __restrict__ accum,   // [NG][DIM]
                                                  float* __restrict__ ssum) {  // [NG]
    __shared__ __align__(16) unsigned short xs[2][8][33][40]; // 42.2 KB, bank-spread pads
    __shared__ float sacc[4][32];
    __shared__ float pbuf[32];
    __shared__ int   gbuf[32];
    __shared__ __align__(16) float redp[4][DIM];

    const int t = threadIdx.x;
    const int wave = t >> 6;
    const int lane = t & 63;
    const int quad = lane >> 4;
    const int lcol = lane & 15;
    const float cn = *cnorm;

    // contiguous tile range for this block: q=20, r=265
    const int b = blockIdx.x;
    const int q = NTILES / GRID_F, r = NTILES % GRID_F;
    const int t0 = b * q + min(b, r);
    const int t1 = t0 + q + (b < r ? 1 : 0);

    // B fragments (bf16 W_att, L2-resident)
    short8 bfrag[8];
    {
        const unsigned short* wr = Wbf + (size_t)(16 * wave + lcol) * DIM + quad * 8;
#pragma unroll
        for (int s = 0; s < 8; ++s) bfrag[s] = *(const short8*)(wr + s * 32);
    }

    // staging map: thread -> row (32 rows x 8 threads), 16B column slot
    const int srow = t >> 3;
    const int soff = (t & 7) * 4;
    // pooling map: lane -> (chunk, col); dim d = ps*32 + pc + k
    const int ps = lane >> 3;
    const int pc = (lane & 7) * 4;

    const float ctxv = ctx[16 * wave + lcol];
    const float bv = b_att[16 * wave + lcol];

    float4 a4 = make_float4(0.f, 0.f, 0.f, 0.f);  // pool accumulator (dims d..d+4)
    float s_acc = 0.f;                            // sum-of-p accumulator (t<32)
    int cur_g = -1;
    int cur = 0;

    auto FLUSH = [&](int gf) {
        *(float4*)&redp[wave][(lane >> 3) * 32 + (lane & 7) * 4] = a4;
        BAR();
        float rsum = (redp[0][t] + redp[1][t]) + (redp[2][t] + redp[3][t]);
        atomicAdd(&accum[(size_t)gf * DIM + t], rsum);
        if (t < 64) {
            float sp = (t < 32) ? s_acc : 0.f;
            sp += __shfl_xor(sp, 1);  sp += __shfl_xor(sp, 2);
            sp += __shfl_xor(sp, 4);  sp += __shfl_xor(sp, 8);
            sp += __shfl_xor(sp, 16);
            if (t == 0) atomicAdd(&ssum[gf], sp);
        }
        BAR();   // redp reusable
    };

    // ---- prologue: stage tile t0 into xs[0]
    {
        const float* xrow = x + (size_t)(t0 * TILE + srow) * DIM + soff;
        float4 h0[8];
#pragma unroll
        for (int s = 0; s < 8; ++s) h0[s] = *(const float4*)(xrow + s * 32);
#pragma unroll
        for (int s = 0; s < 8; ++s) {
            uint2 w;
            w.x = pk_bf2(h0[s].x, h0[s].y);
            w.y = pk_bf2(h0[s].z, h0[s].w);
            *(uint2*)&xs[0][s][srow][soff] = w;
        }
        BAR();
    }

    float4 h[8];
    for (int ti = t0; ti < t1; ++ti) {
        const bool haveNext = (ti + 1 < t1);
        // ---- issue next-tile loads early (in flight across MFMA+epilogue)
        if (haveNext) {
            const float* xrow = x + (size_t)((ti + 1) * TILE + srow) * DIM + soff;
#pragma unroll
            for (int s = 0; s < 8; ++s) h[s] = *(const float4*)(xrow + s * 32);
        }
        const int bval = batch[ti * TILE + (t & 31)];

        // ---- MFMA on xs[cur]: logits[node][attncol]
        floatx4 acc[2];
        acc[0] = (floatx4)0.f; acc[1] = (floatx4)0.f;
#pragma unroll
        for (int s = 0; s < 8; ++s) {
#pragma unroll
            for (int mt = 0; mt < 2; ++mt) {
                short8 afrag = *(const short8*)&xs[cur][s][mt * 16 + lcol][quad * 8];
                acc[mt] = __builtin_amdgcn_mfma_f32_16x16x32_bf16(afrag, bfrag[s], acc[mt], 0, 0, 0);
            }
        }

        // ---- scores: reduce ctx*tanh over this wave's 16 cols
#pragma unroll
        for (int mt = 0; mt < 2; ++mt) {
#pragma unroll
            for (int r4 = 0; r4 < 4; ++r4) {
                float v = ctxv * tanh_fast(acc[mt][r4] + bv);
                v += __shfl_xor(v, 1);
                v += __shfl_xor(v, 2);
                v += __shfl_xor(v, 4);
                v += __shfl_xor(v, 8);
                if (lcol == 0) sacc[wave][mt * 16 + quad * 4 + r4] = v;
            }
        }
        BAR();   // (a) sacc visible; also fences prev-iter pool reads vs write below

        // ---- p/g for this tile + stage-write next tile (concurrent phases)
        if (t < 32) {
            float sres = (sacc[0][t] + sacc[1][t]) + (sacc[2][t] + sacc[3][t]);
            pbuf[t] = __expf(sres - cn);   // |s| <= cn, no segment max needed
            gbuf[t] = bval;
        }
        if (haveNext) {
#pragma unroll
            for (int s = 0; s < 8; ++s) {   // vmcnt auto-wait lands here
                uint2 w;
                w.x = pk_bf2(h[s].x, h[s].y);
                w.y = pk_bf2(h[s].z, h[s].w);
                *(uint2*)&xs[cur ^ 1][s][srow][soff] = w;
            }
        }
        BAR();   // (b) pbuf/gbuf + next tile visible

        // ---- pooling: accumulate in registers, flush on segment change
        const int g0 = gbuf[0];
        const int g1 = gbuf[31];
        if (cur_g < 0) cur_g = g0;
        for (int g = cur_g; g <= g1; ++g) {     // 1 iter except at boundaries
#pragma unroll
            for (int j = 0; j < 8; ++j) {
                int i = (wave << 3) + j;
                float wp = (gbuf[i] == g) ? pbuf[i] : 0.f;   // wave-uniform
                if (wp != 0.f) {
                    uint2 v = *(const uint2*)&xs[cur][ps][i][pc];
                    a4.x += wp * __uint_as_float(v.x << 16);
                    a4.y += wp * __uint_as_float(v.x & 0xffff0000u);
                    a4.z += wp * __uint_as_float(v.y << 16);
                    a4.w += wp * __uint_as_float(v.y & 0xffff0000u);
                }
            }
            if (t < 32) s_acc += (gbuf[t] == g) ? pbuf[t] : 0.f;
            if (g < g1) {
                FLUSH(g);
                a4 = make_float4(0.f, 0.f, 0.f, 0.f);
                s_acc = 0.f;
            }
        }
        cur_g = g1;
        cur ^= 1;
    }
    FLUSH(cur_g);
}

// ---------------- out = (accum/ssum) @ W_out^T + b_out
__global__ __launch_bounds__(256) void k_out(const float* __restrict__ accum,
                                             const float* __restrict__ ssum,
                                             const float* __restrict__ WtOut,
                                             const float* __restrict__ b_out,
                                             float* __restrict__ out) {
    int g = blockIdx.x;
    int t = threadIdx.x;
    __shared__ float pl[256];
    float inv = 1.0f / (ssum[g] + 1e-20f);
    pl[t] = accum[(size_t)g * DIM + t] * inv;
    __syncthreads();
    float acc = b_out[t];
#pragma unroll 4
    for (int d = 0; d < DIM; ++d) acc += pl[d] * WtOut[d * DIM + t];
    out[(size_t)g * DIM + t] = acc;
}

extern "C" void kernel_launch(void* const* d_in, const int* in_sizes, int n_in,
                              void* d_out, int out_size, void* d_ws, size_t ws_size,
                              hipStream_t stream) {
    (void)in_sizes; (void)n_in; (void)out_size; (void)ws_size;
    const float* x     = (const float*)d_in[0];
    const int*   batch = (const int*)d_in[1];
    const float* W_att = (const float*)d_in[2];
    const float* b_att = (const float*)d_in[3];
    const float* ctx   = (const float*)d_in[4];
    const float* W_out = (const float*)d_in[5];
    const float* b_out = (const float*)d_in[6];
    float* out = (float*)d_out;

    float* accum = (float*)d_ws;                         // 131072
    float* ssum  = accum + 131072;                       // 512
    float* Wt    = ssum + 512;                           // 65536
    unsigned short* Wbf = (unsigned short*)(Wt + 65536); // 16384 ushort
    float* cnorm = (float*)(Wbf + 16384);                // 1

    k_prep<<<dim3(835), dim3(256), 0, stream>>>(W_out, W_att, ctx, Wt, Wbf, cnorm, accum);
    k_fused<<<dim3(GRID_F), dim3(256), 0, stream>>>(x, Wbf, b_att, ctx, batch, cnorm, accum, ssum);
    k_out<<<dim3(NG), dim3(256), 0, stream>>>(accum, ssum, Wt, b_out, out);
}